// Round 1
// baseline (1988.662 us; speedup 1.0000x reference)
//
#include <hip/hip_runtime.h>
#include <math.h>

// GCN 2-layer forward on MI355X.
// Factorization: with g = (x@W)*dinv, out[i] = dinv[i]*(sum_{e:dst=i} g[src_e] + g[i]) + b.
// deg[i] = (# incoming edges) + 1 (self loop); dinv = rsqrt(deg).

#define NN 100000
#define NE 3200000

// ---------------- kernels ----------------

__global__ void k_count_deg(const int* __restrict__ dst, int* __restrict__ deg, int E) {
    int i = blockIdx.x * blockDim.x + threadIdx.x;
    if (i < E) atomicAdd(&deg[dst[i]], 1);
}

__global__ void k_dinv(const int* __restrict__ deg, float* __restrict__ dinv, int N) {
    int i = blockIdx.x * blockDim.x + threadIdx.x;
    if (i < N) dinv[i] = rsqrtf((float)(deg[i] + 1));  // +1 self loop
}

// g1[i,:] = (x[i,:] @ W1) * dinv[i]   (x: [N,16], W1: [16,32])
__global__ void k_gemm1(const float* __restrict__ x, const float* __restrict__ W1,
                        const float* __restrict__ dinv, float* __restrict__ g1, int N) {
    __shared__ float Ws[16 * 32];
    for (int t = threadIdx.x; t < 16 * 32; t += blockDim.x) Ws[t] = W1[t];
    __syncthreads();
    int i = blockIdx.x * blockDim.x + threadIdx.x;
    if (i >= N) return;
    const float4* xp = (const float4*)(x + (size_t)i * 16);
    float4 xa = xp[0], xb = xp[1], xc = xp[2], xd = xp[3];
    float xv[16] = {xa.x, xa.y, xa.z, xa.w, xb.x, xb.y, xb.z, xb.w,
                    xc.x, xc.y, xc.z, xc.w, xd.x, xd.y, xd.z, xd.w};
    float acc[32];
#pragma unroll
    for (int j = 0; j < 32; j++) acc[j] = 0.f;
#pragma unroll
    for (int k = 0; k < 16; k++) {
        float xk = xv[k];
#pragma unroll
        for (int j = 0; j < 32; j++) acc[j] = fmaf(xk, Ws[k * 32 + j], acc[j]);
    }
    float s = dinv[i];
    float4* gp = (float4*)(g1 + (size_t)i * 32);
#pragma unroll
    for (int q = 0; q < 8; q++) {
        float4 v;
        v.x = acc[q * 4 + 0] * s;
        v.y = acc[q * 4 + 1] * s;
        v.z = acc[q * 4 + 2] * s;
        v.w = acc[q * 4 + 3] * s;
        gp[q] = v;
    }
}

// 8 threads per edge; each handles 4 of the 32 features.
__global__ void k_agg1(const int* __restrict__ src, const int* __restrict__ dst,
                       const float* __restrict__ g1, float* __restrict__ acc1, int E) {
    int t = blockIdx.x * blockDim.x + threadIdx.x;
    int e = t >> 3;
    if (e >= E) return;
    int f = (t & 7) * 4;
    int s = src[e], d = dst[e];
    float4 v = *(const float4*)(g1 + (size_t)s * 32 + f);
    float* o = acc1 + (size_t)d * 32 + f;
    atomicAdd(o + 0, v.x);
    atomicAdd(o + 1, v.y);
    atomicAdd(o + 2, v.z);
    atomicAdd(o + 3, v.w);
}

// z = relu(dinv*(acc1+g1)+b1) ; g2 = (z @ W2) * dinv   (W2: [32,3])
__global__ void k_layer2(const float* __restrict__ acc1, const float* __restrict__ g1,
                         const float* __restrict__ dinv, const float* __restrict__ b1,
                         const float* __restrict__ W2, float* __restrict__ g2, int N) {
    __shared__ float Ws[32 * 3];
    __shared__ float bs[32];
    if (threadIdx.x < 96) Ws[threadIdx.x] = W2[threadIdx.x];
    if (threadIdx.x < 32) bs[threadIdx.x] = b1[threadIdx.x];
    __syncthreads();
    int i = blockIdx.x * blockDim.x + threadIdx.x;
    if (i >= N) return;
    float di = dinv[i];
    const float4* ap = (const float4*)(acc1 + (size_t)i * 32);
    const float4* gp = (const float4*)(g1 + (size_t)i * 32);
    float o0 = 0.f, o1 = 0.f, o2 = 0.f;
#pragma unroll
    for (int q = 0; q < 8; q++) {
        float4 a = ap[q];
        float4 g = gp[q];
        float zz[4] = {a.x + g.x, a.y + g.y, a.z + g.z, a.w + g.w};
#pragma unroll
        for (int u = 0; u < 4; u++) {
            int j = q * 4 + u;
            float z = fmaf(di, zz[u], bs[j]);
            z = fmaxf(z, 0.f);
            o0 = fmaf(z, Ws[j * 3 + 0], o0);
            o1 = fmaf(z, Ws[j * 3 + 1], o1);
            o2 = fmaf(z, Ws[j * 3 + 2], o2);
        }
    }
    g2[(size_t)i * 3 + 0] = o0 * di;
    g2[(size_t)i * 3 + 1] = o1 * di;
    g2[(size_t)i * 3 + 2] = o2 * di;
}

__global__ void k_agg2(const int* __restrict__ src, const int* __restrict__ dst,
                       const float* __restrict__ g2, float* __restrict__ acc2, int E) {
    int e = blockIdx.x * blockDim.x + threadIdx.x;
    if (e >= E) return;
    int s = src[e], d = dst[e];
    float a = g2[(size_t)s * 3 + 0];
    float b = g2[(size_t)s * 3 + 1];
    float c = g2[(size_t)s * 3 + 2];
    atomicAdd(&acc2[(size_t)d * 3 + 0], a);
    atomicAdd(&acc2[(size_t)d * 3 + 1], b);
    atomicAdd(&acc2[(size_t)d * 3 + 2], c);
}

__global__ void k_final(const float* __restrict__ acc2, const float* __restrict__ g2,
                        const float* __restrict__ dinv, const float* __restrict__ b2,
                        float* __restrict__ out, int N) {
    int i = blockIdx.x * blockDim.x + threadIdx.x;
    if (i >= N) return;
    float di = dinv[i];
    float v0 = fmaf(di, acc2[(size_t)i * 3 + 0] + g2[(size_t)i * 3 + 0], b2[0]);
    float v1 = fmaf(di, acc2[(size_t)i * 3 + 1] + g2[(size_t)i * 3 + 1], b2[1]);
    float v2 = fmaf(di, acc2[(size_t)i * 3 + 2] + g2[(size_t)i * 3 + 2], b2[2]);
    float m = fmaxf(v0, fmaxf(v1, v2));
    float lse = m + logf(expf(v0 - m) + expf(v1 - m) + expf(v2 - m));
    out[(size_t)i * 3 + 0] = v0 - lse;
    out[(size_t)i * 3 + 1] = v1 - lse;
    out[(size_t)i * 3 + 2] = v2 - lse;
}

// ---------------- launch ----------------

extern "C" void kernel_launch(void* const* d_in, const int* in_sizes, int n_in,
                              void* d_out, int out_size, void* d_ws, size_t ws_size,
                              hipStream_t stream) {
    const float* x  = (const float*)d_in[0];
    const int*   ei = (const int*)d_in[1];   // [2, E] int (harness converts integer -> int32)
    const float* W1 = (const float*)d_in[2];
    const float* b1 = (const float*)d_in[3];
    const float* W2 = (const float*)d_in[4];
    const float* b2 = (const float*)d_in[5];
    float* out = (float*)d_out;

    const int* src = ei;
    const int* dst = ei + NE;

    // workspace layout (floats/ints, 4B each):
    // deg[N] | dinv[N] | g1[N*32] | acc1[N*32] | g2[N*3] | acc2[N*3]  => 28.8 MB
    char* ws = (char*)d_ws;
    int*   deg  = (int*)ws;
    float* dinv = (float*)(ws + (size_t)4 * NN);
    float* g1   = dinv + NN;
    float* acc1 = g1 + (size_t)NN * 32;
    float* g2   = acc1 + (size_t)NN * 32;
    float* acc2 = g2 + (size_t)NN * 3;

    // zero the atomic targets (d_ws is poisoned before every call)
    hipMemsetAsync(deg,  0, (size_t)NN * 4, stream);
    hipMemsetAsync(acc1, 0, (size_t)NN * 32 * 4, stream);
    hipMemsetAsync(acc2, 0, (size_t)NN * 3 * 4, stream);

    const int B = 256;
    int gbN = (NN + B - 1) / B;
    int gbE = (NE + B - 1) / B;

    k_count_deg<<<gbE, B, 0, stream>>>(dst, deg, NE);
    k_dinv<<<gbN, B, 0, stream>>>(deg, dinv, NN);
    k_gemm1<<<gbN, B, 0, stream>>>(x, W1, dinv, g1, NN);

    int gbA1 = ((NE * 8) + B - 1) / B;  // 8 threads per edge
    k_agg1<<<gbA1, B, 0, stream>>>(src, dst, g1, acc1, NE);

    k_layer2<<<gbN, B, 0, stream>>>(acc1, g1, dinv, b1, W2, g2, NN);
    k_agg2<<<gbE, B, 0, stream>>>(src, dst, g2, acc2, NE);
    k_final<<<gbN, B, 0, stream>>>(acc2, g2, dinv, b2, out, NN);
}

// Round 2
// 769.032 us; speedup vs baseline: 2.5859x; 2.5859x over previous
//
#include <hip/hip_runtime.h>
#include <math.h>

// GCN 2-layer forward on MI355X — CSR counting-sort edition (no float atomics).
// Factorization: with g = (x@W)*dinv, out[i] = dinv[i]*(sum_{e:dst=i} g[src_e] + g[i]) + b.
// deg[i] = (# incoming edges) + 1 (self loop); dinv = rsqrt(deg).
//
// Pipeline: count(int atomics) -> scan(rowptr,dinv,cursor) -> scatter(col)
//           -> gemm1(g1 = x@W1 * dinv)
//           -> L1 fused: wave/node CSR-sum(g1) + relu + @W2 + scale -> g2
//           -> L2 fused: wave/node CSR-sum(g2) + bias + log_softmax -> out

#define NN 100000
#define NE 3200000

// ---------------- kernels ----------------

__global__ void k_count_deg(const int* __restrict__ dst, int* __restrict__ deg, int E) {
    int i = blockIdx.x * blockDim.x + threadIdx.x;
    if (i < E) atomicAdd(&deg[dst[i]], 1);
}

// Single-workgroup device scan: rowptr = exclusive_scan(deg), cursor = rowptr,
// dinv = rsqrt(deg+1). 1024 threads, wave-shuffle scan (3 barriers/chunk).
__global__ void k_scan(const int* __restrict__ deg, int* __restrict__ rowptr,
                       int* __restrict__ cursor, float* __restrict__ dinv, int N) {
    __shared__ int wsum[16];
    __shared__ int carry_s;
    int tid = threadIdx.x;           // 0..1023
    int lane = tid & 63, w = tid >> 6;
    if (tid == 0) carry_s = 0;
    __syncthreads();
    for (int base = 0; base < N; base += 1024) {
        int i = base + tid;
        int v = (i < N) ? deg[i] : 0;
        int incl = v;
#pragma unroll
        for (int off = 1; off < 64; off <<= 1) {
            int t = __shfl_up(incl, off);
            if (lane >= off) incl += t;
        }
        if (lane == 63) wsum[w] = incl;
        __syncthreads();
        if (w == 0 && lane < 16) {
            int wv = wsum[lane];
            int winc = wv;
#pragma unroll
            for (int off = 1; off < 16; off <<= 1) {
                int t = __shfl_up(winc, off);
                if (lane >= off) winc += t;
            }
            wsum[lane] = winc - wv;  // exclusive wave offset
        }
        __syncthreads();
        int carry = carry_s;
        int excl = incl - v + wsum[w];
        if (i < N) {
            int r = carry + excl;
            rowptr[i] = r;
            cursor[i] = r;
            dinv[i] = rsqrtf((float)(v + 1));  // +1 self loop
        }
        __syncthreads();
        if (tid == 1023) carry_s = carry + excl + v;
        __syncthreads();
    }
    if (threadIdx.x == 0) rowptr[N] = carry_s;
}

__global__ void k_scatter(const int* __restrict__ src, const int* __restrict__ dst,
                          int* __restrict__ cursor, int* __restrict__ col, int E) {
    int e = blockIdx.x * blockDim.x + threadIdx.x;
    if (e >= E) return;
    int pos = atomicAdd(&cursor[dst[e]], 1);
    col[pos] = src[e];
}

// g1[i,:] = (x[i,:] @ W1) * dinv[i]   (x: [N,16], W1: [16,32])
__global__ void k_gemm1(const float* __restrict__ x, const float* __restrict__ W1,
                        const float* __restrict__ dinv, float* __restrict__ g1, int N) {
    __shared__ float Ws[16 * 32];
    for (int t = threadIdx.x; t < 16 * 32; t += blockDim.x) Ws[t] = W1[t];
    __syncthreads();
    int i = blockIdx.x * blockDim.x + threadIdx.x;
    if (i >= N) return;
    const float4* xp = (const float4*)(x + (size_t)i * 16);
    float4 xa = xp[0], xb = xp[1], xc = xp[2], xd = xp[3];
    float xv[16] = {xa.x, xa.y, xa.z, xa.w, xb.x, xb.y, xb.z, xb.w,
                    xc.x, xc.y, xc.z, xc.w, xd.x, xd.y, xd.z, xd.w};
    float acc[32];
#pragma unroll
    for (int j = 0; j < 32; j++) acc[j] = 0.f;
#pragma unroll
    for (int k = 0; k < 16; k++) {
        float xk = xv[k];
#pragma unroll
        for (int j = 0; j < 32; j++) acc[j] = fmaf(xk, Ws[k * 32 + j], acc[j]);
    }
    float s = dinv[i];
    float4* gp = (float4*)(g1 + (size_t)i * 32);
#pragma unroll
    for (int q = 0; q < 8; q++) {
        float4 v;
        v.x = acc[q * 4 + 0] * s;
        v.y = acc[q * 4 + 1] * s;
        v.z = acc[q * 4 + 2] * s;
        v.w = acc[q * 4 + 3] * s;
        gp[q] = v;
    }
}

// Layer-1 fused: one wave per node. Lanes 0..31 own feature f (x2 edge halves),
// CSR-sum g1[src] rows, add self, relu(dinv*sum+b1), then z@W2 via shuffle
// reduce -> g2[node,0..2] = (z@W2)*dinv.
__global__ void k_l1(const int* __restrict__ rowptr, const int* __restrict__ col,
                     const float* __restrict__ g1, const float* __restrict__ dinv,
                     const float* __restrict__ b1, const float* __restrict__ W2,
                     float* __restrict__ g2, int N) {
    int wid = (int)((blockIdx.x * (size_t)blockDim.x + threadIdx.x) >> 6);  // node
    if (wid >= N) return;  // wave-uniform
    int lane = threadIdx.x & 63;
    int half = lane >> 5, f = lane & 31;
    int beg = rowptr[wid], end = rowptr[wid + 1];
    float acc = 0.f;
    for (int j = beg + half; j < end; j += 2) {
        int s = col[j];                      // broadcast within each half-wave
        acc += g1[(size_t)s * 32 + f];       // 128B coalesced row
    }
    acc += __shfl_down(acc, 32);             // fold halves (lanes 0..31 valid)
    float di = dinv[wid];
    float z = 0.f;
    if (half == 0) {
        float self = g1[(size_t)wid * 32 + f];
        z = fmaxf(fmaf(di, acc + self, b1[f]), 0.f);
    }
    float o0 = z * W2[f * 3 + 0];
    float o1 = z * W2[f * 3 + 1];
    float o2 = z * W2[f * 3 + 2];
#pragma unroll
    for (int off = 16; off >= 1; off >>= 1) {
        o0 += __shfl_down(o0, off);
        o1 += __shfl_down(o1, off);
        o2 += __shfl_down(o2, off);
    }
    if (lane == 0) {
        g2[(size_t)wid * 3 + 0] = o0 * di;
        g2[(size_t)wid * 3 + 1] = o1 * di;
        g2[(size_t)wid * 3 + 2] = o2 * di;
    }
}

// Layer-2 fused: one wave per node. 64 lanes stride edges, 3 accumulators,
// shuffle reduce, + self + bias, log_softmax, write out[node,0..2].
__global__ void k_l2(const int* __restrict__ rowptr, const int* __restrict__ col,
                     const float* __restrict__ g2, const float* __restrict__ dinv,
                     const float* __restrict__ b2, float* __restrict__ out, int N) {
    int wid = (int)((blockIdx.x * (size_t)blockDim.x + threadIdx.x) >> 6);
    if (wid >= N) return;
    int lane = threadIdx.x & 63;
    int beg = rowptr[wid], end = rowptr[wid + 1];
    float a0 = 0.f, a1 = 0.f, a2 = 0.f;
    for (int j = beg + lane; j < end; j += 64) {
        int s = col[j];
        a0 += g2[(size_t)s * 3 + 0];
        a1 += g2[(size_t)s * 3 + 1];
        a2 += g2[(size_t)s * 3 + 2];
    }
#pragma unroll
    for (int off = 32; off >= 1; off >>= 1) {
        a0 += __shfl_down(a0, off);
        a1 += __shfl_down(a1, off);
        a2 += __shfl_down(a2, off);
    }
    if (lane == 0) {
        float di = dinv[wid];
        float v0 = fmaf(di, a0 + g2[(size_t)wid * 3 + 0], b2[0]);
        float v1 = fmaf(di, a1 + g2[(size_t)wid * 3 + 1], b2[1]);
        float v2 = fmaf(di, a2 + g2[(size_t)wid * 3 + 2], b2[2]);
        float m = fmaxf(v0, fmaxf(v1, v2));
        float lse = m + logf(expf(v0 - m) + expf(v1 - m) + expf(v2 - m));
        out[(size_t)wid * 3 + 0] = v0 - lse;
        out[(size_t)wid * 3 + 1] = v1 - lse;
        out[(size_t)wid * 3 + 2] = v2 - lse;
    }
}

// ---------------- launch ----------------

extern "C" void kernel_launch(void* const* d_in, const int* in_sizes, int n_in,
                              void* d_out, int out_size, void* d_ws, size_t ws_size,
                              hipStream_t stream) {
    const float* x  = (const float*)d_in[0];
    const int*   ei = (const int*)d_in[1];   // [2, E] int32 (harness-converted)
    const float* W1 = (const float*)d_in[2];
    const float* b1 = (const float*)d_in[3];
    const float* W2 = (const float*)d_in[4];
    const float* b2 = (const float*)d_in[5];
    float* out = (float*)d_out;

    const int* src = ei;
    const int* dst = ei + NE;

    // workspace (4B units): col[E] | g1[N*32] | g2[N*3] | deg[N] | cursor[N] | dinv[N] | rowptr[N+1]
    // (everything before rowptr is a multiple of 4 elements -> 16B alignment for float4 on g1)
    int*   col    = (int*)d_ws;
    float* g1     = (float*)(col + (size_t)NE);
    float* g2     = g1 + (size_t)NN * 32;
    int*   deg    = (int*)(g2 + (size_t)NN * 3);
    int*   cursor = deg + NN;
    float* dinv   = (float*)(cursor + NN);
    int*   rowptr = (int*)(dinv + NN);

    hipMemsetAsync(deg, 0, (size_t)NN * 4, stream);

    const int B = 256;
    int gbN = (NN + B - 1) / B;
    int gbE = (NE + B - 1) / B;
    int gbW = (NN * 64 + B - 1) / B;  // one wave per node

    k_count_deg<<<gbE, B, 0, stream>>>(dst, deg, NE);
    k_scan<<<1, 1024, 0, stream>>>(deg, rowptr, cursor, dinv, NN);
    k_scatter<<<gbE, B, 0, stream>>>(src, dst, cursor, col, NE);
    k_gemm1<<<gbN, B, 0, stream>>>(x, W1, dinv, g1, NN);
    k_l1<<<gbW, B, 0, stream>>>(rowptr, col, g1, dinv, b1, W2, g2, NN);
    k_l2<<<gbW, B, 0, stream>>>(rowptr, col, g2, dinv, b2, out, NN);
}